// Round 3
// baseline (215.432 us; speedup 1.0000x reference)
//
#include <hip/hip_runtime.h>

#define DM 2048
#define BB 64
#define SS 32
#define CC 8

// Interleaved-transposed A layout ("a4"): a4[(k>>2)*256 + b*4 + (k&3)] = A[b][k]
// A wave float4 load at quad-index (k4*64 + lane) yields lane=b, k = 4*k4..4*k4+3.

// K1: ut4 = sum_c controls[c][b][k], written in a4 layout.
__global__ void k1_sum_transpose(const float* __restrict__ controls,
                                 float* __restrict__ ut4) {
  const int b = blockIdx.x >> 2;
  const int k = (blockIdx.x & 3) * 512 + threadIdx.x * 4;
  float4 s = make_float4(0.f, 0.f, 0.f, 0.f);
#pragma unroll
  for (int c = 0; c < CC; ++c) {
    const float4 v = *reinterpret_cast<const float4*>(
        controls + ((size_t)c * BB + b) * DM + k);
    s.x += v.x; s.y += v.y; s.z += v.z; s.w += v.w;
  }
  *reinterpret_cast<float4*>(ut4 + (k >> 2) * 256 + b * 4) = s;
}

// GEMM v3: C[e][b] = sum_k W[e][k]*A[b][k], A in a4 layout.
// grid 1024: e-tile = (bid&127)*16, kp = bid>>7 (k-range 256).
// 4 waves/block; wave wv owns e-rows e0+wv*4..+3. lane = b.
// W staged to LDS coalesced (reg-staged, double-buffered), read back as
// wave-uniform ds_read_b128 broadcasts. No barriers in main loop (each wave
// stages exactly the rows it consumes).
// TR=0: part[kp][e][b]   TR=1: part[kp][b][e] (LDS-transposed epilogue)
template <int TR>
__global__ __launch_bounds__(256, 4) void gemm_bcast(
    const float* __restrict__ a4, const float* __restrict__ w,
    float* __restrict__ part) {
  __shared__ float lw[2][16][64];   // 8 KB double-buffered W tile
  __shared__ float red[16][64];     // TR=1 transpose scratch

  const int t    = threadIdx.x;
  const int lane = t & 63;
  const int wv   = t >> 6;
  const int e0   = (blockIdx.x & 127) * 16;
  const int kp   = blockIdx.x >> 7;
  const int k0   = kp * 256;

  // Staging: thread t loads W[e0 + (t>>4)][k0 + s*64 + (t&15)*4 .. +3]
  const int srow = t >> 4;
  const int scol = (t & 15) * 4;
  const float* sgp = w + (size_t)(e0 + srow) * DM + k0 + scol;

  // A: per-stage 16 float4 per lane from a4 (L2-resident)
  const float4* ap =
      reinterpret_cast<const float4*>(a4) + (size_t)(k0 >> 2) * 64 + lane;

  float acc[4] = {0.f, 0.f, 0.f, 0.f};
  float4 wst = *reinterpret_cast<const float4*>(sgp);  // stage 0

#pragma unroll
  for (int s = 0; s < 4; ++s) {
    // commit staged W to LDS buffer s&1
    *reinterpret_cast<float4*>(&lw[s & 1][srow][scol]) = wst;
    if (s < 3) wst = *reinterpret_cast<const float4*>(sgp + (s + 1) * 64);

    // load A chunk for this stage (64 k per lane)
    float4 a[16];
#pragma unroll
    for (int q = 0; q < 16; ++q) a[q] = ap[(s * 16 + q) * 64];

    // compute: wave-uniform LDS broadcasts of own rows
#pragma unroll
    for (int i = 0; i < 4; ++i) {
      const float* wrow = &lw[s & 1][wv * 4 + i][0];
#pragma unroll
      for (int q = 0; q < 16; ++q) {
        const float4 ww = *reinterpret_cast<const float4*>(wrow + q * 4);
        acc[i] += a[q].x * ww.x + a[q].y * ww.y + a[q].z * ww.z + a[q].w * ww.w;
      }
    }
  }

  if (TR == 0) {
#pragma unroll
    for (int i = 0; i < 4; ++i)
      part[((size_t)kp * DM + e0 + wv * 4 + i) * 64 + lane] = acc[i];
  } else {
#pragma unroll
    for (int i = 0; i < 4; ++i) red[wv * 4 + i][lane] = acc[i];
    __syncthreads();
    const int b  = t >> 2;
    const int e4 = (t & 3) * 4;
    const float4 v = make_float4(red[e4 + 0][b], red[e4 + 1][b],
                                 red[e4 + 2][b], red[e4 + 3][b]);
    *reinterpret_cast<float4*>(part + ((size_t)kp * 64 + b) * DM + e0 + e4) = v;
  }
}

// R1: a4out[(e>>2)*256 + b*4 + (e&3)] = sum_kp part[kp][e][b] + 8*bias[e]
__global__ void reduce_to_a4(const float* __restrict__ part,
                             const float* __restrict__ bias,
                             float* __restrict__ out4) {
  const int idx = blockIdx.x * 256 + threadIdx.x;  // 32768
  const int b = idx & 63, eq = idx >> 6;
  float s[4];
#pragma unroll
  for (int i = 0; i < 4; ++i) {
    const int e = eq * 4 + i;
    float v = 8.0f * bias[e];
#pragma unroll
    for (int kp = 0; kp < 8; ++kp)
      v += part[((size_t)kp * DM + e) * 64 + b];
    s[i] = v;
  }
  *reinterpret_cast<float4*>(out4 + eq * 256 + b * 4) =
      make_float4(s[0], s[1], s[2], s[3]);
}

// R2: pt2[b][e] = sum_kp part_t[kp][b][e] + 8*bias[e]
__global__ void reduce_to_pt(const float* __restrict__ part_t,
                             const float* __restrict__ bias,
                             float* __restrict__ pt2) {
  const int idx = blockIdx.x * 256 + threadIdx.x;  // 131072
  const int e = idx & 2047;
  const int b = idx >> 11;
  float v = 8.0f * bias[e];
#pragma unroll
  for (int kp = 0; kp < 8; ++kp)
    v += part_t[((size_t)kp * 64 + b) * DM + e];
  pt2[idx] = v;
}

// K4: out[b][s][e] = seq[b][s][e] + pt2[b][e]
__global__ void k4_broadcast_add(const float* __restrict__ seq,
                                 const float* __restrict__ pt2,
                                 float* __restrict__ out) {
  const int bi = blockIdx.x;
  const int b  = bi >> 5;
  const int s0 = ((bi >> 1) & 15) * 2;
  const int e  = (bi & 1) * 1024 + threadIdx.x * 4;
  const float4 pv = *reinterpret_cast<const float4*>(pt2 + (size_t)b * DM + e);
  const size_t base = ((size_t)b * SS + s0) * DM + e;
  const float4 q0 = *reinterpret_cast<const float4*>(seq + base);
  const float4 q1 = *reinterpret_cast<const float4*>(seq + base + DM);
  *reinterpret_cast<float4*>(out + base) =
      make_float4(q0.x + pv.x, q0.y + pv.y, q0.z + pv.z, q0.w + pv.w);
  *reinterpret_cast<float4*>(out + base + DM) =
      make_float4(q1.x + pv.x, q1.y + pv.y, q1.z + pv.z, q1.w + pv.w);
}

extern "C" void kernel_launch(void* const* d_in, const int* in_sizes, int n_in,
                              void* d_out, int out_size, void* d_ws,
                              size_t ws_size, hipStream_t stream) {
  const float* seq      = (const float*)d_in[0];
  const float* controls = (const float*)d_in[1];
  // d_in[2..5] = Wq, bq, Wk, bk — mathematically unused (softmax over size-1 axis == 1)
  const float* Wv = (const float*)d_in[6];
  const float* bv = (const float*)d_in[7];
  const float* Wo = (const float*)d_in[8];
  const float* bo = (const float*)d_in[9];
  float* out = (float*)d_out;

  char* ws = (char*)d_ws;
  float* ut4  = (float*)(ws);                    // 512 KB
  float* vt4  = (float*)(ws + (512ull << 10));   // 512 KB
  float* pt2  = (float*)(ws + (1024ull << 10));  // 512 KB  [64][2048]
  float* part = (float*)(ws + (1536ull << 10));  // 4 MB    [8][2048][64] or [8][64][2048]

  k1_sum_transpose<<<256, 128, 0, stream>>>(controls, ut4);
  gemm_bcast<0><<<1024, 256, 0, stream>>>(ut4, Wv, part);
  reduce_to_a4<<<128, 256, 0, stream>>>(part, bv, vt4);
  gemm_bcast<1><<<1024, 256, 0, stream>>>(vt4, Wo, part);
  reduce_to_pt<<<512, 256, 0, stream>>>(part, bo, pt2);
  k4_broadcast_add<<<2048, 256, 0, stream>>>(seq, pt2, out);
}

// Round 4
// 73.798 us; speedup vs baseline: 2.9192x; 2.9192x over previous
//
#include <hip/hip_runtime.h>

#define DM 2048
#define BB 64
#define SS 32
#define CC 8
#define KP 16   // k-split factor
#define KR 128  // k-range per block
#define LWP 4   // LDS row pad (floats)

// K1: u[b][k] = sum_c controls[c][b][k]  (plain row-major)
__global__ void k1_sum(const float* __restrict__ controls,
                       float* __restrict__ u) {
  const int b = blockIdx.x >> 2;
  const int k = (blockIdx.x & 3) * 512 + threadIdx.x * 4;
  float4 s = make_float4(0.f, 0.f, 0.f, 0.f);
#pragma unroll
  for (int c = 0; c < CC; ++c) {
    const float4 v = *reinterpret_cast<const float4*>(
        controls + ((size_t)c * BB + b) * DM + k);
    s.x += v.x; s.y += v.y; s.z += v.z; s.w += v.w;
  }
  *reinterpret_cast<float4*>(u + (size_t)b * DM + k) = s;
}

// GEMM, lane=e mapping: C[e][b] = sum_k W[e][k] * A[b][k].
// W: per-lane operand — staged coalesced into LDS, read as ds_read_b128.
// A: wave-uniform operand — row-major, addresses depend only on
//    blockIdx + readfirstlane(wave-id) -> compiler emits s_load to SGPRs;
//    v_fma takes the SGPR source directly. No large VGPR arrays (r3 spill fix).
// Block: 512 thr = 8 waves. Waves 0-3: k-sub 0, b-group wv*16.
//        Waves 4-7: k-sub 1, b-group (wv-4)*16. Pair-reduced via LDS.
// grid 512: et = bid&31 (64 e), kp = bid>>5 (KR k).
// part[kp][b][e]
__global__ __launch_bounds__(512, 4) void gemm_we(
    const float* __restrict__ a, const float* __restrict__ w,
    float* __restrict__ part) {
  __shared__ float lw[64][KR + LWP];
  __shared__ float red[4][16][64];

  const int t  = threadIdx.x;
  const int et = blockIdx.x & 31;
  const int kp = blockIdx.x >> 5;
  const int e0 = et * 64;
  const int k0 = kp * KR;

  // stage W[e0+0..63][k0..k0+KR) coalesced: 32 threads x float4 per row
  {
    const int row = t >> 5;
    const int col = (t & 31) * 4;
#pragma unroll
    for (int r8 = 0; r8 < 64; r8 += 16) {
      const float4 v = *reinterpret_cast<const float4*>(
          w + (size_t)(e0 + r8 + row) * DM + k0 + col);
      *reinterpret_cast<float4*>(&lw[r8 + row][col]) = v;
    }
  }
  __syncthreads();

  const int lane = t & 63;
  const int bg = __builtin_amdgcn_readfirstlane((t >> 6) & 3) * 16;
  const int ks = __builtin_amdgcn_readfirstlane(t >> 8) * 64;  // 0 or 64

  float acc[16];
#pragma unroll
  for (int i = 0; i < 16; ++i) acc[i] = 0.f;

  const float* abase = a + k0 + ks;  // + b*DM + kk (all uniform)

  for (int kk = 0; kk < 64; kk += 16) {
    const float4 w0 = *reinterpret_cast<const float4*>(&lw[lane][ks + kk]);
    const float4 w1 = *reinterpret_cast<const float4*>(&lw[lane][ks + kk + 4]);
    const float4 w2 = *reinterpret_cast<const float4*>(&lw[lane][ks + kk + 8]);
    const float4 w3 = *reinterpret_cast<const float4*>(&lw[lane][ks + kk + 12]);
#pragma unroll
    for (int b = 0; b < 16; ++b) {
      const float* ab = abase + (size_t)(bg + b) * DM + kk;
      const float4 a0 = *reinterpret_cast<const float4*>(ab);
      const float4 a1 = *reinterpret_cast<const float4*>(ab + 4);
      const float4 a2 = *reinterpret_cast<const float4*>(ab + 8);
      const float4 a3 = *reinterpret_cast<const float4*>(ab + 12);
      acc[b] += w0.x * a0.x + w0.y * a0.y + w0.z * a0.z + w0.w * a0.w +
                w1.x * a1.x + w1.y * a1.y + w1.z * a1.z + w1.w * a1.w +
                w2.x * a2.x + w2.y * a2.y + w2.z * a2.z + w2.w * a2.w +
                w3.x * a3.x + w3.y * a3.y + w3.z * a3.z + w3.w * a3.w;
    }
  }

  // pair-reduce k-sub halves: waves 4-7 dump, waves 0-3 combine + write
  const int wv = t >> 6;
  if (wv >= 4) {
#pragma unroll
    for (int b = 0; b < 16; ++b) red[wv - 4][b][lane] = acc[b];
  }
  __syncthreads();
  if (wv < 4) {
#pragma unroll
    for (int b = 0; b < 16; ++b) {
      const float v = acc[b] + red[wv][b][lane];
      part[((size_t)kp * BB + bg + b) * DM + e0 + lane] = v;
    }
  }
}

// reduce over kp + C*bias -> outm[b][e] row-major
__global__ void reduce_bias(const float* __restrict__ part,
                            const float* __restrict__ bias,
                            float* __restrict__ outm) {
  const int idx = blockIdx.x * 256 + threadIdx.x;  // 131072
  const int e = idx & 2047;
  const int b = idx >> 11;
  float v = 8.0f * bias[e];
#pragma unroll
  for (int kp = 0; kp < KP; ++kp)
    v += part[((size_t)kp * BB + b) * DM + e];
  outm[idx] = v;
}

// K4: out[b][s][e] = seq[b][s][e] + pt2[b][e]
__global__ void k4_broadcast_add(const float* __restrict__ seq,
                                 const float* __restrict__ pt2,
                                 float* __restrict__ out) {
  const int bi = blockIdx.x;
  const int b  = bi >> 5;
  const int s0 = ((bi >> 1) & 15) * 2;
  const int e  = (bi & 1) * 1024 + threadIdx.x * 4;
  const float4 pv = *reinterpret_cast<const float4*>(pt2 + (size_t)b * DM + e);
  const size_t base = ((size_t)b * SS + s0) * DM + e;
  const float4 q0 = *reinterpret_cast<const float4*>(seq + base);
  const float4 q1 = *reinterpret_cast<const float4*>(seq + base + DM);
  *reinterpret_cast<float4*>(out + base) =
      make_float4(q0.x + pv.x, q0.y + pv.y, q0.z + pv.z, q0.w + pv.w);
  *reinterpret_cast<float4*>(out + base + DM) =
      make_float4(q1.x + pv.x, q1.y + pv.y, q1.z + pv.z, q1.w + pv.w);
}

extern "C" void kernel_launch(void* const* d_in, const int* in_sizes, int n_in,
                              void* d_out, int out_size, void* d_ws,
                              size_t ws_size, hipStream_t stream) {
  const float* seq      = (const float*)d_in[0];
  const float* controls = (const float*)d_in[1];
  // d_in[2..5] = Wq, bq, Wk, bk — mathematically unused (softmax over size-1 axis == 1)
  const float* Wv = (const float*)d_in[6];
  const float* bv = (const float*)d_in[7];
  const float* Wo = (const float*)d_in[8];
  const float* bo = (const float*)d_in[9];
  float* out = (float*)d_out;

  char* ws = (char*)d_ws;
  float* u    = (float*)(ws);                    // 512 KB [64][2048]
  float* v    = (float*)(ws + (512ull << 10));   // 512 KB [64][2048]
  float* pt2  = (float*)(ws + (1024ull << 10));  // 512 KB [64][2048]
  float* part = (float*)(ws + (1536ull << 10));  // 8 MB   [16][64][2048]

  k1_sum<<<256, 128, 0, stream>>>(controls, u);
  gemm_we<<<512, 512, 0, stream>>>(u, Wv, part);
  reduce_bias<<<512, 256, 0, stream>>>(part, bv, v);
  gemm_we<<<512, 512, 0, stream>>>(v, Wo, part);
  reduce_bias<<<512, 256, 0, stream>>>(part, bo, pt2);
  k4_broadcast_add<<<2048, 256, 0, stream>>>(seq, pt2, out);
}

// Round 5
// 41.221 us; speedup vs baseline: 5.2263x; 1.7903x over previous
//
#include <hip/hip_runtime.h>
#include <hip/hip_bf16.h>

#define DM 2048
#define BB 64
#define SS 32
#define CC 8
#define KP 8    // k-split across blocks
#define KR 256  // k-range per block

typedef __attribute__((ext_vector_type(8))) short short8;
typedef __attribute__((ext_vector_type(4))) short short4v;
typedef __attribute__((ext_vector_type(4))) float f32x4;

static __device__ __forceinline__ short f2bf(float f) {
  union { __hip_bfloat16 h; short s; } u;
  u.h = __float2bfloat16(f);  // RNE; compiler emits v_cvt_pk_bf16_f32 pairs
  return u.s;
}

// K1: u16[b][k] = bf16(sum_c controls[c][b][k]).  grid 128 x 256
__global__ void k1_sum_bf16(const float* __restrict__ controls,
                            short* __restrict__ u16) {
  const int idx = blockIdx.x * 256 + threadIdx.x;  // 32768 = 64b * 512 kq
  const int b = idx >> 9;
  const int k = (idx & 511) * 4;
  float4 s = make_float4(0.f, 0.f, 0.f, 0.f);
#pragma unroll
  for (int c = 0; c < CC; ++c) {
    const float4 v = *reinterpret_cast<const float4*>(
        controls + ((size_t)c * BB + b) * DM + k);
    s.x += v.x; s.y += v.y; s.z += v.z; s.w += v.w;
  }
  short4v o = {f2bf(s.x), f2bf(s.y), f2bf(s.z), f2bf(s.w)};
  *reinterpret_cast<short4v*>(u16 + (size_t)b * DM + k) = o;
}

// MFMA GEMM: part[kp][b][e] = sum_{k in kp} A[b][k] * W[e][k]
// A: bf16 row-major [64][2048] (L2-resident).  W: fp32 row-major, cvt on fly.
// mfma_f32_16x16x32_bf16: A-frag lane l -> (m = l&15, k = 8*(l>>4)+j)
//                         B-frag lane l -> (n = l&15, k = 8*(l>>4)+j)
//                         D lane l, reg j -> (m = (l>>4)*4+j, n = l&15)
// Wave = 64b x 16e x 256k (4 m-tiles, 32 MFMA). Block = 4 waves = 64e.
// grid 256: eblk = bid&31, kp = bid>>5. No LDS, no barriers, no uniform loads.
__global__ __launch_bounds__(256, 1) void gemm_mfma(
    const short* __restrict__ abf, const float* __restrict__ w,
    float* __restrict__ part) {
  const int t    = threadIdx.x;
  const int lane = t & 63;
  const int wv   = t >> 6;
  const int e0   = (blockIdx.x & 31) * 64 + wv * 16;
  const int kp   = blockIdx.x >> 5;
  const int k0   = kp * KR;

  const int r  = lane & 15;        // m for A-frags, n(=e) for B-frag
  const int kc = (lane >> 4) * 8;  // k sub-offset within 32

  f32x4 acc0 = {0.f, 0.f, 0.f, 0.f}, acc1 = {0.f, 0.f, 0.f, 0.f};
  f32x4 acc2 = {0.f, 0.f, 0.f, 0.f}, acc3 = {0.f, 0.f, 0.f, 0.f};

  const float* wp = w + (size_t)(e0 + r) * DM + k0 + kc;
  const short* ap = abf + (size_t)r * DM + k0 + kc;

#pragma unroll
  for (int s = 0; s < KR / 32; ++s) {
    const int ko = s * 32;
    const float4 wlo = *reinterpret_cast<const float4*>(wp + ko);
    const float4 whi = *reinterpret_cast<const float4*>(wp + ko + 4);
    short8 bfrag;
    bfrag[0] = f2bf(wlo.x); bfrag[1] = f2bf(wlo.y);
    bfrag[2] = f2bf(wlo.z); bfrag[3] = f2bf(wlo.w);
    bfrag[4] = f2bf(whi.x); bfrag[5] = f2bf(whi.y);
    bfrag[6] = f2bf(whi.z); bfrag[7] = f2bf(whi.w);
    const short8 a0 = *reinterpret_cast<const short8*>(ap + ko);
    const short8 a1 = *reinterpret_cast<const short8*>(ap + (size_t)16 * DM + ko);
    const short8 a2 = *reinterpret_cast<const short8*>(ap + (size_t)32 * DM + ko);
    const short8 a3 = *reinterpret_cast<const short8*>(ap + (size_t)48 * DM + ko);
    acc0 = __builtin_amdgcn_mfma_f32_16x16x32_bf16(a0, bfrag, acc0, 0, 0, 0);
    acc1 = __builtin_amdgcn_mfma_f32_16x16x32_bf16(a1, bfrag, acc1, 0, 0, 0);
    acc2 = __builtin_amdgcn_mfma_f32_16x16x32_bf16(a2, bfrag, acc2, 0, 0, 0);
    acc3 = __builtin_amdgcn_mfma_f32_16x16x32_bf16(a3, bfrag, acc3, 0, 0, 0);
  }

  const int brow = (lane >> 4) * 4;
  float* pb = part + ((size_t)kp * BB) * DM + e0 + r;
#pragma unroll
  for (int j = 0; j < 4; ++j) {
    pb[(size_t)(brow + j) * DM]      = acc0[j];
    pb[(size_t)(brow + j + 16) * DM] = acc1[j];
    pb[(size_t)(brow + j + 32) * DM] = acc2[j];
    pb[(size_t)(brow + j + 48) * DM] = acc3[j];
  }
}

// R1: v16[b][e] = bf16(sum_kp part[kp][b][e] + 8*bias[e]).  grid 128 x 256
__global__ void reduce_bias_bf16(const float* __restrict__ part,
                                 const float* __restrict__ bias,
                                 short* __restrict__ v16) {
  const int idx = blockIdx.x * 256 + threadIdx.x;  // 32768
  const int b = idx >> 9;
  const int e = (idx & 511) * 4;
  const float4 bb = *reinterpret_cast<const float4*>(bias + e);
  float4 s = make_float4(8.f * bb.x, 8.f * bb.y, 8.f * bb.z, 8.f * bb.w);
#pragma unroll
  for (int kp = 0; kp < KP; ++kp) {
    const float4 p = *reinterpret_cast<const float4*>(
        part + ((size_t)kp * BB + b) * DM + e);
    s.x += p.x; s.y += p.y; s.z += p.z; s.w += p.w;
  }
  short4v o = {f2bf(s.x), f2bf(s.y), f2bf(s.z), f2bf(s.w)};
  *reinterpret_cast<short4v*>(v16 + (size_t)b * DM + e) = o;
}

// K4 fused: out[b][s][e] = seq[b][s][e] + (sum_kp part[kp][b][e] + 8*bo[e])
// grid 256: b = bid>>2, e-quarter = bid&3 (512 e). block 256:
// thread covers e-quad (t&127), s-half s0 = t>>7, 16 s-iterations.
__global__ void k4_fused(const float* __restrict__ seq,
                         const float* __restrict__ part,
                         const float* __restrict__ bias,
                         float* __restrict__ out) {
  const int b  = blockIdx.x >> 2;
  const int e  = (blockIdx.x & 3) * 512 + (threadIdx.x & 127) * 4;
  const int s0 = threadIdx.x >> 7;
  const float4 bb = *reinterpret_cast<const float4*>(bias + e);
  float4 pv = make_float4(8.f * bb.x, 8.f * bb.y, 8.f * bb.z, 8.f * bb.w);
#pragma unroll
  for (int kp = 0; kp < KP; ++kp) {
    const float4 p = *reinterpret_cast<const float4*>(
        part + ((size_t)kp * BB + b) * DM + e);
    pv.x += p.x; pv.y += p.y; pv.z += p.z; pv.w += p.w;
  }
  const size_t base = (size_t)b * SS * DM + e;
#pragma unroll 4
  for (int i = 0; i < 16; ++i) {
    const size_t off = base + (size_t)(s0 + 2 * i) * DM;
    const float4 q = *reinterpret_cast<const float4*>(seq + off);
    *reinterpret_cast<float4*>(out + off) =
        make_float4(q.x + pv.x, q.y + pv.y, q.z + pv.z, q.w + pv.w);
  }
}

extern "C" void kernel_launch(void* const* d_in, const int* in_sizes, int n_in,
                              void* d_out, int out_size, void* d_ws,
                              size_t ws_size, hipStream_t stream) {
  const float* seq      = (const float*)d_in[0];
  const float* controls = (const float*)d_in[1];
  // d_in[2..5] = Wq, bq, Wk, bk — mathematically unused (softmax over size-1 axis == 1)
  const float* Wv = (const float*)d_in[6];
  const float* bv = (const float*)d_in[7];
  const float* Wo = (const float*)d_in[8];
  const float* bo = (const float*)d_in[9];
  float* out = (float*)d_out;

  char* ws = (char*)d_ws;
  short* u16  = (short*)(ws);                    // 256 KB bf16 [64][2048]
  short* v16  = (short*)(ws + (256ull << 10));   // 256 KB bf16 [64][2048]
  float* part = (float*)(ws + (1024ull << 10));  // 4 MB fp32 [8][64][2048]

  k1_sum_bf16<<<128, 256, 0, stream>>>(controls, u16);
  gemm_mfma<<<256, 256, 0, stream>>>(u16, Wv, part);
  reduce_bias_bf16<<<128, 256, 0, stream>>>(part, bv, v16);
  gemm_mfma<<<256, 256, 0, stream>>>(v16, Wo, part);
  k4_fused<<<256, 256, 0, stream>>>(seq, part, bo, out);
}